// Round 15
// baseline (381.076 us; speedup 1.0000x reference)
//
#include <hip/hip_runtime.h>
#include <hip/hip_bf16.h>
#include <stdint.h>

#define NN 100000
#define EE 1600000
#define NBK 391        // fill blocks, 4096 edges each
#define CHUNK 4096
#define NCB 98         // coarse buckets of 1024 nodes (98*1024 >= NN)
#define NPROJ 1563     // (NN+63)/64 proj blocks
#define NS 32          // mred splits (part2 rows; k_proj atomics fold directly)

typedef __attribute__((ext_vector_type(8))) short bf16x8;
typedef __attribute__((ext_vector_type(4))) float f32x4;
typedef __attribute__((ext_vector_type(2))) float f32x2;
union FragU { uint4 u; bf16x8 h; };

__device__ inline unsigned pack_bf2(float a, float b) {
  __hip_bfloat162 t;
  t.x = __float2bfloat16(a);
  t.y = __float2bfloat16(b);
  return *reinterpret_cast<unsigned*>(&t);
}

// unpack a bf16 pair (uint) into f32x2 — 2 VALU; pairs feed v_pk_fma_f32/v_pk_add_f32
__device__ inline f32x2 unpk2(unsigned u) {
  f32x2 r;
  r.x = __uint_as_float(u << 16);
  r.y = __uint_as_float(u & 0xffff0000u);
  return r;
}

// ---------------- per-block LDS histogram over 98 coarse buckets ----------------
__launch_bounds__(256)
__global__ void k_hist(const int* __restrict__ ei, int* __restrict__ histmat) {
  __shared__ int hist[NCB];
  int t = threadIdx.x;
  if (t < NCB) hist[t] = 0;
  __syncthreads();
  int base = blockIdx.x * CHUNK;
  int nb = EE - base; if (nb > CHUNK) nb = CHUNK;
  for (int k = t; k < nb; k += 256)
    atomicAdd(&hist[ei[EE + base + k] >> 10], 1);
  __syncthreads();
  if (t < NCB) histmat[blockIdx.x * NCB + t] = hist[t];
}

// ---------------- scan (fused col-sums + bucket bases + per-bucket cursor scan) ----
// Round-15: k_sumcb folded in — each block computes the 98 column sums itself
// (L2-hot redundant reads), killing one launch on the serial critical path.
__launch_bounds__(512)
__global__ void k_ppos(const int* __restrict__ histmat,
                       int* __restrict__ bstart, int* __restrict__ offsets,
                       int* __restrict__ ppos) {
  __shared__ int sm[512];
  __shared__ int sb[128];
  int cb = blockIdx.x, t = threadIdx.x;
  if (t < 128) {
    int s = 0;
    if (t < NCB) {
      for (int blk = 0; blk < NBK; blk++) s += histmat[blk * NCB + t];
    }
    sb[t] = s;
  }
  __syncthreads();
  for (int off = 1; off < 128; off <<= 1) {
    int x = (t < 128 && t >= off) ? sb[t - off] : 0;
    __syncthreads();
    if (t < 128) sb[t] += x;
    __syncthreads();
  }
  int bs = (cb == 0) ? 0 : sb[cb - 1];  // exclusive prefix (inclusive scan of prev)
  if (t == 0) bstart[cb] = bs;
  if (cb == 0 && t == 0) { bstart[NCB] = EE; offsets[NN] = EE; }
  int v = (t < NBK) ? histmat[t * NCB + cb] : 0;
  sm[t] = v;
  __syncthreads();
  for (int off = 1; off < 512; off <<= 1) {
    int x = (t >= off) ? sm[t - off] : 0;
    __syncthreads();
    sm[t] += x;
    __syncthreads();
  }
  if (t < NBK) ppos[cb * NBK + t] = bs + sm[t] - v;
}

// ---------------- fill pass B: LDS radix-partition + contiguous run copy ----------------
__launch_bounds__(256)
__global__ void k_fill_b(const int* __restrict__ ei, const int* __restrict__ ppos,
                         unsigned* __restrict__ brec) {
  __shared__ int hist[NCB], binstart[NCB], bincur[NCB], pbase[NCB];
  __shared__ unsigned lbuf[CHUNK];
  __shared__ unsigned char cbArr[CHUNK];
  int t = threadIdx.x;
  int base = blockIdx.x * CHUNK;
  int nb = EE - base; if (nb > CHUNK) nb = CHUNK;
  if (t < NCB) { hist[t] = 0; pbase[t] = ppos[t * NBK + blockIdx.x]; }
  __syncthreads();
  unsigned rec[16]; int rcb[16]; int cnt = 0;
  for (int k = t; k < nb; k += 256) {
    int s = ei[base + k], d = ei[EE + base + k];
    rec[cnt] = (unsigned)s | ((unsigned)(d & 1023) << 17);  // s < 2^17, dlocal 10b
    rcb[cnt] = d >> 10;
    atomicAdd(&hist[rcb[cnt]], 1);
    cnt++;
  }
  __syncthreads();
  if (t < NCB) binstart[t] = hist[t];
  __syncthreads();
  for (int off = 1; off < NCB; off <<= 1) {
    int v = (t < NCB && t >= off) ? binstart[t - off] : 0;
    __syncthreads();
    if (t < NCB) binstart[t] += v;
    __syncthreads();
  }
  if (t < NCB) { binstart[t] -= hist[t]; bincur[t] = 0; }
  __syncthreads();
  for (int i = 0; i < cnt; i++) {
    int c = rcb[i];
    int pos = atomicAdd(&bincur[c], 1);
    int p = binstart[c] + pos;
    lbuf[p] = rec[i];
    cbArr[p] = (unsigned char)c;
  }
  __syncthreads();
  for (int i = t; i < nb; i += 256) {
    int c = cbArr[i];
    brec[pbase[c] + (i - binstart[c])] = lbuf[i];
  }
}

// ---------------- fill pass C: bucket histogram + scan + place + FUSED x-prep ----------------
// Round-15: k_prep folded into the tail — this block just produced dinv for its
// 1024 nodes; after __syncthreads (global-visibility within block) it converts
// their x rows to bf16*dinv. Kills one launch.
__launch_bounds__(1024)
__global__ void k_fill_c(const unsigned* __restrict__ brec, const int* __restrict__ bstart,
                         int* __restrict__ csr, int* __restrict__ offsets,
                         float* __restrict__ dinv,
                         const float* __restrict__ x, unsigned* __restrict__ xbf2) {
  __shared__ int cnt[1024], sm[1024];
  int cbk = blockIdx.x, t = threadIdx.x;
  int nb0 = cbk << 10;
  int nn = NN - nb0; if (nn > 1024) nn = 1024;
  cnt[t] = 0;
  __syncthreads();
  int e0 = bstart[cbk], e1 = bstart[cbk + 1];
  for (int j = e0 + t; j < e1; j += 1024)
    atomicAdd(&cnt[brec[j] >> 17], 1);
  __syncthreads();
  int cv = cnt[t];
  sm[t] = cv;
  __syncthreads();
  for (int off = 1; off < 1024; off <<= 1) {
    int v = (t >= off) ? sm[t - off] : 0;
    __syncthreads();
    sm[t] += v;
    __syncthreads();
  }
  sm[t] -= cv;  // exclusive
  float dvmine = rsqrtf((float)(cv + 1));
  if (t < nn) {
    offsets[nb0 + t] = e0 + sm[t];
    dinv[nb0 + t] = dvmine;  // deg includes self loop
  }
  cnt[t] = 0;  // reuse as placement cursor
  __syncthreads();
  for (int j = e0 + t; j < e1; j += 1024) {
    unsigned r = brec[j];
    int dl = r >> 17;
    int p = atomicAdd(&cnt[dl], 1);
    csr[e0 + sm[dl] + p] = r & 0x1FFFF;  // confined to this bucket's window
  }
  // ---- fused x-prep for this block's nodes (dinv visible after barrier) ----
  __syncthreads();
  int npairs = nn * 32;
  for (int idx = t; idx < npairs; idx += 1024) {
    int i = nb0 * 32 + idx;           // global pair index
    float dv = dinv[nb0 + (idx >> 5)];
    float2 v = ((const float2*)x)[i];
    xbf2[i] = pack_bf2(v.x * dv, v.y * dv);
  }
}

// ---------------- ax = A_norm @ x (8-lane-group gather, 2x unrolled) ----------------
__launch_bounds__(256)
__global__ void k_agg_x(const unsigned* __restrict__ xbf2, const int* __restrict__ offsets,
                        const int* __restrict__ csr, const float* __restrict__ dinv,
                        unsigned* __restrict__ axb) {
  int gid = blockIdx.x * 256 + threadIdx.x;
  int n = gid >> 6;
  if (n >= NN) return;
  int lane = gid & 63, q = lane & 7, grp = lane >> 3;
  int e0 = offsets[n], e1 = offsets[n + 1];
  float dv = dinv[n];
  f32x2 a2[4];
#pragma unroll
  for (int i = 0; i < 4; i++) a2[i] = (f32x2){0.f, 0.f};
  if (grp == 0) {  // self loop, counted once
    uint4 u = ((const uint4*)(xbf2 + (size_t)n * 32))[q];
    unsigned uu[4] = {u.x, u.y, u.z, u.w};
#pragma unroll
    for (int p = 0; p < 4; p++) a2[p] += unpk2(uu[p]);
  }
  int b2 = e0;
  for (; b2 + 8 < e1; b2 += 16) {
    int j0 = b2 + grp, j1 = j0 + 8;
    int s0 = csr[j0];
    bool ok1 = j1 < e1;
    int s1 = ok1 ? csr[j1] : s0;
    uint4 u0 = ((const uint4*)(xbf2 + (size_t)s0 * 32))[q];
    uint4 u1 = ((const uint4*)(xbf2 + (size_t)s1 * 32))[q];
    unsigned w0[4] = {u0.x, u0.y, u0.z, u0.w};
    unsigned w1[4] = {u1.x, u1.y, u1.z, u1.w};
#pragma unroll
    for (int p = 0; p < 4; p++) a2[p] += unpk2(w0[p]);
    if (ok1) {
#pragma unroll
      for (int p = 0; p < 4; p++) a2[p] += unpk2(w1[p]);
    }
  }
  for (; b2 < e1; b2 += 8) {
    int j = b2 + grp;
    if (j < e1) {
      int s = csr[j];
      uint4 u = ((const uint4*)(xbf2 + (size_t)s * 32))[q];
      unsigned uu[4] = {u.x, u.y, u.z, u.w};
#pragma unroll
      for (int p = 0; p < 4; p++) a2[p] += unpk2(uu[p]);
    }
  }
#pragma unroll
  for (int i = 0; i < 4; i++) {
    a2[i].x += __shfl_xor(a2[i].x, 8);
    a2[i].x += __shfl_xor(a2[i].x, 16);
    a2[i].x += __shfl_xor(a2[i].x, 32);
    a2[i].y += __shfl_xor(a2[i].y, 8);
    a2[i].y += __shfl_xor(a2[i].y, 16);
    a2[i].y += __shfl_xor(a2[i].y, 32);
  }
  if (lane < 8) {
    uint4 u;
    u.x = pack_bf2(a2[0].x * dv, a2[0].y * dv);
    u.y = pack_bf2(a2[1].x * dv, a2[1].y * dv);
    u.z = pack_bf2(a2[2].x * dv, a2[2].y * dv);
    u.w = pack_bf2(a2[3].x * dv, a2[3].y * dv);
    ((uint4*)(axb + (size_t)n * 32))[q] = u;
  }
}

// ---------------- fused weights + MLP weight repack ----------------
// Wt[208 cols][64 k] bf16 k-pair packed + bb[208]  (blocks 0..16)
// blocks 17..32: W1b[128 cols][64 k];  blocks 33..48: W2b[64 cols][128 k]
__launch_bounds__(256)
__global__ void k_fusew(const float* __restrict__ gcnK_W, const float* __restrict__ gcnK_b,
                        const float* __restrict__ gcnV_W, const float* __restrict__ gcnV_b,
                        const float* __restrict__ mha_in_w, const float* __restrict__ mha_in_b,
                        const float* __restrict__ gat_W, const float* __restrict__ sQ,
                        const float* __restrict__ t1W, const float* __restrict__ t2W,
                        unsigned* __restrict__ Wt, float* __restrict__ bb,
                        unsigned* __restrict__ W1b, unsigned* __restrict__ W2b) {
  __shared__ float sW1[64 * 65];   // gcnV_W (blk<16) / gcnK_W (blk16), 65-padded
  __shared__ float sW2[64 * 65];   // V-rows dense 8x64 (blk<8) / gat_W padded (blk 8-15) / K-rows padded (blk16)
  __shared__ float sW3[64 * 65];   // Q-rows padded (blk16 only)
  __shared__ float sqq[640], qhs[640], Ms[5120], kb[64];
  int blk = blockIdx.x, t = threadIdx.x;
  const float scale = 0.35355339059327373f;  // 1/sqrt(8)
  if (blk < 16) {
    for (int i = t; i < 4096; i += 256) sW1[(i >> 6) * 65 + (i & 63)] = gcnV_W[i];
    if (blk < 8) {
      // this block's 8 V columns: mha_in_w rows 128+blk*8 .. +7 (dense 8x64)
      for (int i = t; i < 512; i += 256) sW2[i] = mha_in_w[(128 + blk * 8) * 64 + i];
    } else {
      for (int i = t; i < 4096; i += 256) sW2[(i >> 6) * 65 + (i & 63)] = gat_W[i];
    }
    __syncthreads();
    int idx = blk * 256 + t;        // 0..4095
    int d = idx >> 5, kp = idx & 31;
    float v2[2];
#pragma unroll
    for (int u2 = 0; u2 < 2; u2++) {
      int k = kp * 2 + u2;
      float s = 0.f;
      if (d < 64) {
        int r = d & 7;
        for (int j = 0; j < 64; j++) s = fmaf(sW1[k * 65 + j], sW2[r * 64 + j], s);
      } else {
        int c = d - 64;
        for (int j = 0; j < 64; j++) s = fmaf(sW1[k * 65 + j], sW2[j * 65 + c], s);
      }
      v2[u2] = s;
    }
    Wt[idx] = pack_bf2(v2[0], v2[1]);
    // biases for this block's 8 output columns
    if (t < 8) {
      if (blk < 8) {
        int d0 = blk * 8 + t;
        float s = mha_in_b[128 + d0];
        for (int j = 0; j < 64; j++) s = fmaf(gcnV_b[j], sW2[t * 64 + j], s);
        bb[d0] = s;
      } else {
        int c = (blk - 8) * 8 + t;
        float s = 0.f;
        for (int j = 0; j < 64; j++) s = fmaf(gcnV_b[j], sW2[j * 65 + c], s);
        bb[64 + c] = s;
      }
    }
  } else if (blk == 16) {
    // ---- single block: Z cols + Z biases, all operands LDS-staged ----
    for (int i = t; i < 4096; i += 256) {
      int r = i >> 6, c = i & 63;
      sW1[r * 65 + c] = gcnK_W[i];
      sW2[r * 65 + c] = mha_in_w[64 * 64 + i];  // K rows 64..127
      sW3[r * 65 + c] = mha_in_w[i];            // Q rows 0..63
    }
    for (int i = t; i < 640; i += 256) sqq[i] = sQ[i];
    __syncthreads();
    // stage A: qhs[lv*64+c] = (sQ[lv]·Wq[c] + bq[c]) * scale ; kb = K-proj bias
    for (int e = t; e < 640; e += 256) {
      int lv = e >> 6, c = e & 63;
      float acc = mha_in_b[c];
      for (int i = 0; i < 64; i++) acc = fmaf(sqq[lv * 64 + i], sW3[c * 65 + i], acc);
      qhs[e] = acc * scale;
    }
    if (t < 64) {
      float s = mha_in_b[64 + t];
      for (int j = 0; j < 64; j++) s = fmaf(gcnK_b[j], sW2[t * 65 + j], s);
      kb[t] = s;
    }
    __syncthreads();
    // stage B: M[j][hl] = sum_c Wk_row(64+cp)[j] * qhs[lv][cp] ; bz
    for (int e = t; e < 5120; e += 256) {
      int j = e / 80, hl = e % 80;
      int h = hl / 10, lv = hl % 10;
      float s = 0.f;
#pragma unroll
      for (int c = 0; c < 8; c++) {
        int cp = h * 8 + c;
        s = fmaf(sW2[cp * 65 + j], qhs[lv * 64 + cp], s);
      }
      Ms[j * 80 + hl] = s;
    }
    if (t < 80) {
      int h = t / 10, lv = t % 10;
      float s = 0.f;
#pragma unroll
      for (int c = 0; c < 8; c++) {
        int cp = h * 8 + c;
        s = fmaf(kb[cp], qhs[lv * 64 + cp], s);
      }
      bb[128 + t] = s;
    }
    __syncthreads();
    // stage C: Wz[k][hl] = sum_j gcnK_W[k][j] * M[j][hl]
    for (int e = t; e < 2560; e += 256) {
      int hl = e >> 5, kp = e & 31;
      float v2[2];
#pragma unroll
      for (int u2 = 0; u2 < 2; u2++) {
        int k = kp * 2 + u2;
        float s = 0.f;
        for (int j = 0; j < 64; j++) s = fmaf(sW1[k * 65 + j], Ms[j * 80 + hl], s);
        v2[u2] = s;
      }
      Wt[(128 + hl) * 32 + kp] = pack_bf2(v2[0], v2[1]);
    }
  } else if (blk < 33) {
    // ---- W1b: t1_W [64 k][128 c] -> [col][k] bf16 k-pair packed ----
    int idx = (blk - 17) * 256 + t;   // 0..4095
    int col = idx >> 5, kp = idx & 31;
    W1b[idx] = pack_bf2(t1W[(2 * kp) * 128 + col], t1W[(2 * kp + 1) * 128 + col]);
  } else {
    // ---- W2b: t2_W [128 k][64 c] -> [col][k] bf16 k-pair packed ----
    int idx = (blk - 33) * 256 + t;   // 0..4095
    int col = idx >> 6, kp = idx & 63;
    W2b[idx] = pack_bf2(t2W[(2 * kp) * 64 + col], t2W[(2 * kp + 1) * 64 + col]);
  }
}

// ---------------- k_proj (MFMA): X[64x64] @ Wt^T[64x208] -> V,G,Z tiles ----------------
__launch_bounds__(256)
__global__ void k_proj(const unsigned* __restrict__ axb, const unsigned* __restrict__ Wt,
                       const float* __restrict__ bb, const float* __restrict__ a_dst,
                       unsigned char* __restrict__ hG8,
                       float* __restrict__ s_dstv, float* __restrict__ part2) {
  __shared__ float red[4][720];                 // 11520 B  per-wave s/o partials
  int t = threadIdx.x;
  int wid = t >> 6, l = t & 63;
  int l15 = l & 15, lg = l >> 4;
  int base = blockIdx.x * 64;
  int rowbase = base + wid * 16;

  // ---- A fragments (2 K-steps), rows >= NN zeroed ----
  FragU a0, a1;
  {
    int r = rowbase + l15;
    if (r < NN) {
      const uint4* p = (const uint4*)(axb + (size_t)r * 32);
      a0.u = p[lg];
      a1.u = p[4 + lg];
    } else {
      a0.u = make_uint4(0u, 0u, 0u, 0u);
      a1.u = a0.u;
    }
  }
  // ---- GEMM: 13 col-tiles x 2 K-steps ----
  f32x4 acc[13];
#pragma unroll
  for (int ct = 0; ct < 13; ct++) acc[ct] = (f32x4){0.f, 0.f, 0.f, 0.f};
#pragma unroll
  for (int ct = 0; ct < 13; ct++) {
    const uint4* wp = (const uint4*)(Wt + (size_t)(ct * 16 + l15) * 32);
    FragU b0, b1;
    b0.u = wp[lg];
    b1.u = wp[4 + lg];
    acc[ct] = __builtin_amdgcn_mfma_f32_16x16x32_bf16(a0.h, b0.h, acc[ct], 0, 0, 0);
    acc[ct] = __builtin_amdgcn_mfma_f32_16x16x32_bf16(a1.h, b1.h, acc[ct], 0, 0, 0);
  }

  // ---- G epilogue: hg = acc+bias -> fp8 store + sd = hg . a_dst ----
  float sdp[4] = {0.f, 0.f, 0.f, 0.f};
#pragma unroll
  for (int gt = 0; gt < 4; gt++) {
    int col = gt * 16 + l15;
    float bias = bb[64 + col];
    float ad = a_dst[col];
#pragma unroll
    for (int r = 0; r < 4; r++) {
      float hg = acc[4 + gt][r] + bias;
      sdp[r] = fmaf(hg, ad, sdp[r]);
      int row = rowbase + lg * 4 + r;
      if (row < NN) {
        unsigned wq = __builtin_amdgcn_cvt_pk_fp8_f32(hg, hg, 0u, false);
        hG8[(size_t)row * 64 + col] = (unsigned char)(wq & 0xffu);
      }
    }
  }
#pragma unroll
  for (int r = 0; r < 4; r++) {
    float v = sdp[r];
    v += __shfl_xor(v, 1); v += __shfl_xor(v, 2);
    v += __shfl_xor(v, 4); v += __shfl_xor(v, 8);
    int row = rowbase + lg * 4 + r;
    if (l15 == 0 && row < NN) s_dstv[row] = v;
  }

  // ---- Z phase: w = exp(z) kept in REGISTERS; s partials -> red (exact f32) ----
  float wz[5][4];
#pragma unroll
  for (int zt = 0; zt < 5; zt++) {
    int zcol = zt * 16 + l15;       // 0..79 = h*10+lv
    float bias = bb[128 + zcol];
    float sp = 0.f;
#pragma unroll
    for (int r = 0; r < 4; r++) {
      int row = rowbase + lg * 4 + r;
      float z = acc[8 + zt][r] + bias;
      float w = (row < NN) ? __expf(z) : 0.f;
      wz[zt][r] = w;
      sp += w;
    }
    sp += __shfl_xor(sp, 16);
    sp += __shfl_xor(sp, 32);
    if (l < 16) {
      int h = zcol / 10, lv = zcol % 10;
      red[wid][h * 90 + lv] = sp;
    }
  }

  // ---- O phase on matrix pipe: o[hl][c] = sum_row w[row][hl]*vv[row][c] ----
  int sA = (l15 + 32 * lg) & 63;        // source lane for rows 8lg..8lg+3
  int sB2 = (sA + 16) & 63;             // source lane for rows 8lg+4..8lg+7
  bool loK = (lg < 2);
  FragU af[5];
#pragma unroll
  for (int zt = 0; zt < 5; zt++) {
    unsigned wlo = pack_bf2(wz[zt][0], wz[zt][1]);
    unsigned whi = pack_bf2(wz[zt][2], wz[zt][3]);
    unsigned f0 = __shfl(wlo, sA), f1 = __shfl(whi, sA);
    unsigned f2 = __shfl(wlo, sB2), f3 = __shfl(whi, sB2);
    af[zt].u.x = loK ? f0 : 0u;
    af[zt].u.y = loK ? f1 : 0u;
    af[zt].u.z = loK ? f2 : 0u;
    af[zt].u.w = loK ? f3 : 0u;
  }
#pragma unroll
  for (int vt = 0; vt < 4; vt++) {
    float bias = bb[vt * 16 + l15];
    unsigned vlo = pack_bf2(acc[vt][0] + bias, acc[vt][1] + bias);
    unsigned vhi = pack_bf2(acc[vt][2] + bias, acc[vt][3] + bias);
    FragU bf;
    {
      unsigned f0 = __shfl(vlo, sA), f1 = __shfl(vhi, sA);
      unsigned f2 = __shfl(vlo, sB2), f3 = __shfl(vhi, sB2);
      bf.u.x = loK ? f0 : 0u;
      bf.u.y = loK ? f1 : 0u;
      bf.u.z = loK ? f2 : 0u;
      bf.u.w = loK ? f3 : 0u;
    }
    f32x4 oacc[5];
#pragma unroll
    for (int zt = 0; zt < 5; zt++) {
      oacc[zt] = (f32x4){0.f, 0.f, 0.f, 0.f};
      oacc[zt] = __builtin_amdgcn_mfma_f32_16x16x32_bf16(af[zt].h, bf.h, oacc[zt], 0, 0, 0);
    }
    // D-layout: o[hl = zt*16+lg*4+reg][c = vt*16+l15]; keep only head-matched c
#pragma unroll
    for (int zt = 0; zt < 5; zt++) {
#pragma unroll
      for (int r = 0; r < 4; r++) {
        int hl = zt * 16 + lg * 4 + r;
        int h = hl / 10, lv = hl - h * 10;
        if (vt * 2 + (l15 >> 3) == h)
          red[wid][h * 90 + 10 + lv * 8 + (l15 & 7)] = oacc[zt][r];
      }
    }
  }

  // ---- fold 4 waves -> part2 split (atomic; coalesced per block) ----
  __syncthreads();
  float* p2 = part2 + (size_t)(blockIdx.x & (NS - 1)) * 720;
  for (int j = t; j < 720; j += 256) {
    float v = red[0][j] + red[1][j] + red[2][j] + red[3][j];
    atomicAdd(&p2[j], v);
  }
}

// ---------------- context (merged mred2): fold 32 splits -> softmax -> a_eff ----
__global__ void k_context(const float* __restrict__ part2, const float* __restrict__ out_w,
                          const float* __restrict__ out_b, const float* __restrict__ a_src,
                          const float* __restrict__ gat_Wc, float* __restrict__ aeff) {
  __shared__ float po[640], cl[640], ctx[64], ac[720];
  int t = threadIdx.x;  // blockDim = 640
  for (int j = t; j < 720; j += 640) {
    float v = 0.f;
#pragma unroll
    for (int s = 0; s < NS; s++) v += part2[(size_t)s * 720 + j];
    int cg = j / 90, r = j % 90;
    ac[(r < 10) ? (cg * 10 + r) : (80 + cg * 80 + (r - 10))] = v;
  }
  __syncthreads();
  {
    int h = t / 80, r = t % 80, l = r >> 3, j = r & 7;
    po[l * 64 + h * 8 + j] = ac[80 + t] / ac[h * 10 + l];
  }
  __syncthreads();
  {
    int l = t >> 6, d = t & 63;
    float v = out_b[d];
    for (int c = 0; c < 64; c++) v = fmaf(po[l * 64 + c], out_w[d * 64 + c], v);
    cl[t] = v;
  }
  __syncthreads();
  if (t < 64) {
    float m = 0.f;
#pragma unroll
    for (int l = 0; l < 10; l++) m += cl[l * 64 + t];
    ctx[t] = m * 0.1f;
  }
  __syncthreads();
  if (t < 64) {
    float v = a_src[t];
    for (int i = 0; i < 64; i++) v = fmaf(ctx[i], gat_Wc[i * 64 + t], v);
    aeff[t] = v;
  }
}

// ---------------- s_src[n] = dot(hG8[n], a_eff)  (fp8 rows) ----------------
__launch_bounds__(256)
__global__ void k_ssrc(const unsigned char* __restrict__ hG8, const float* __restrict__ aeff,
                       float* __restrict__ s_src) {
  int gid = blockIdx.x * 256 + threadIdx.x;
  int n = gid >> 6, lane = gid & 63;
  if (n >= NN) return;
  unsigned b = hG8[(size_t)n * 64 + lane];
  float v = __builtin_amdgcn_cvt_f32_fp8(b, 0) * aeff[lane];
#pragma unroll
  for (int off = 32; off > 0; off >>= 1) v += __shfl_xor(v, off);
  if (lane == 0) s_src[n] = v;
}

// ---------------- GAT: 8-lane-group gather over fp8 rows -> bf16 output ----------------
__launch_bounds__(256)
__global__ void k_gat(const int* __restrict__ offsets, const int* __restrict__ csr,
                      const float* __restrict__ s_src, const float* __restrict__ s_dstv,
                      const unsigned char* __restrict__ hG8, const float* __restrict__ gat_b,
                      unsigned* __restrict__ gb) {
  int gid = blockIdx.x * 256 + threadIdx.x;
  int n = gid >> 6;
  if (n >= NN) return;
  int lane = gid & 63, q = lane & 7, grp = lane >> 3;
  int e0 = offsets[n], e1 = offsets[n + 1];
  float sd = s_dstv[n];
  float den = 0.f;
  f32x2 a2[4];
#pragma unroll
  for (int i = 0; i < 4; i++) a2[i] = (f32x2){0.f, 0.f};
  int b2 = e0;
  for (; b2 + 8 < e1; b2 += 16) {
    int j0 = b2 + grp, j1 = j0 + 8;
    int s0 = csr[j0];
    bool ok1 = j1 < e1;
    int s1 = ok1 ? csr[j1] : s0;
    float z0 = s_src[s0] + sd;
    float z1 = s_src[s1] + sd;
    uint2 u0 = ((const uint2*)(hG8 + (size_t)s0 * 64))[q];
    uint2 u1 = ((const uint2*)(hG8 + (size_t)s1 * 64))[q];
    z0 = z0 > 0.f ? z0 : 0.2f * z0;
    float ex0 = __expf(z0);  // logits O(1): softmax shift-invariant, skip segment-max
    den += ex0;
    f32x2 e0v = (f32x2){ex0, ex0};
    {
      f32x2 p0 = __builtin_amdgcn_cvt_pk_f32_fp8(u0.x, false);
      f32x2 p1 = __builtin_amdgcn_cvt_pk_f32_fp8(u0.x, true);
      f32x2 p2 = __builtin_amdgcn_cvt_pk_f32_fp8(u0.y, false);
      f32x2 p3 = __builtin_amdgcn_cvt_pk_f32_fp8(u0.y, true);
      a2[0] = e0v * p0 + a2[0];
      a2[1] = e0v * p1 + a2[1];
      a2[2] = e0v * p2 + a2[2];
      a2[3] = e0v * p3 + a2[3];
    }
    if (ok1) {
      z1 = z1 > 0.f ? z1 : 0.2f * z1;
      float ex1 = __expf(z1);
      den += ex1;
      f32x2 e1v = (f32x2){ex1, ex1};
      f32x2 p0 = __builtin_amdgcn_cvt_pk_f32_fp8(u1.x, false);
      f32x2 p1 = __builtin_amdgcn_cvt_pk_f32_fp8(u1.x, true);
      f32x2 p2 = __builtin_amdgcn_cvt_pk_f32_fp8(u1.y, false);
      f32x2 p3 = __builtin_amdgcn_cvt_pk_f32_fp8(u1.y, true);
      a2[0] = e1v * p0 + a2[0];
      a2[1] = e1v * p1 + a2[1];
      a2[2] = e1v * p2 + a2[2];
      a2[3] = e1v * p3 + a2[3];
    }
  }
  for (; b2 < e1; b2 += 8) {
    int j = b2 + grp;
    if (j < e1) {
      int s = csr[j];
      float z = s_src[s] + sd;
      z = z > 0.f ? z : 0.2f * z;
      float ex = __expf(z);
      den += ex;
      uint2 u = ((const uint2*)(hG8 + (size_t)s * 64))[q];
      f32x2 ev = (f32x2){ex, ex};
      f32x2 p0 = __builtin_amdgcn_cvt_pk_f32_fp8(u.x, false);
      f32x2 p1 = __builtin_amdgcn_cvt_pk_f32_fp8(u.x, true);
      f32x2 p2 = __builtin_amdgcn_cvt_pk_f32_fp8(u.y, false);
      f32x2 p3 = __builtin_amdgcn_cvt_pk_f32_fp8(u.y, true);
      a2[0] = ev * p0 + a2[0];
      a2[1] = ev * p1 + a2[1];
      a2[2] = ev * p2 + a2[2];
      a2[3] = ev * p3 + a2[3];
    }
  }
  den += __shfl_xor(den, 8);
  den += __shfl_xor(den, 16);
  den += __shfl_xor(den, 32);
#pragma unroll
  for (int i = 0; i < 4; i++) {
    a2[i].x += __shfl_xor(a2[i].x, 8);
    a2[i].x += __shfl_xor(a2[i].x, 16);
    a2[i].x += __shfl_xor(a2[i].x, 32);
    a2[i].y += __shfl_xor(a2[i].y, 8);
    a2[i].y += __shfl_xor(a2[i].y, 16);
    a2[i].y += __shfl_xor(a2[i].y, 32);
  }
  float inv = 1.f / (den + 1e-16f);
  if (lane < 8) {
    uint4 u;
    u.x = pack_bf2(a2[0].x * inv + gat_b[q * 8 + 0], a2[0].y * inv + gat_b[q * 8 + 1]);
    u.y = pack_bf2(a2[1].x * inv + gat_b[q * 8 + 2], a2[1].y * inv + gat_b[q * 8 + 3]);
    u.z = pack_bf2(a2[2].x * inv + gat_b[q * 8 + 4], a2[2].y * inv + gat_b[q * 8 + 5]);
    u.w = pack_bf2(a2[3].x * inv + gat_b[q * 8 + 6], a2[3].y * inv + gat_b[q * 8 + 7]);
    ((uint4*)(gb + (size_t)n * 32))[q] = u;
  }
}

// ---------------- FUSED MLP (MFMA): out = relu(relu(g@W1+b1)@W2+b2) ----------------
// Round-15: mlp1+mlp2 in one kernel. Stage-1 D-layout output goes relu+bf16
// into a per-wave LDS tile (136-short rows: <=2-way bank aliasing, free per
// m136), re-read as stage-2 A-frags — h1 never touches global (51MB saved).
__launch_bounds__(256)
__global__ void k_mlp(const unsigned* __restrict__ gb, const unsigned* __restrict__ W1b,
                      const float* __restrict__ b1, const unsigned* __restrict__ W2b,
                      const float* __restrict__ b2, float* __restrict__ out) {
  __shared__ unsigned short sh[4][16][136];   // 17408 B
  int t = threadIdx.x;
  int wid = t >> 6, l = t & 63;
  int l15 = l & 15, lg = l >> 4;
  int rowbase = blockIdx.x * 64 + wid * 16;
  // ---- stage 1: g @ W1 ----
  FragU a0, a1;
  {
    int r = rowbase + l15;
    if (r < NN) {
      const uint4* p = (const uint4*)(gb + (size_t)r * 32);
      a0.u = p[lg];
      a1.u = p[4 + lg];
    } else {
      a0.u = make_uint4(0u, 0u, 0u, 0u);
      a1.u = a0.u;
    }
  }
  f32x4 acc1[8];
#pragma unroll
  for (int ct = 0; ct < 8; ct++) acc1[ct] = (f32x4){0.f, 0.f, 0.f, 0.f};
#pragma unroll
  for (int ct = 0; ct < 8; ct++) {
    const uint4* wp = (const uint4*)(W1b + (size_t)(ct * 16 + l15) * 32);
    FragU b0, b1f;
    b0.u = wp[lg];
    b1f.u = wp[4 + lg];
    acc1[ct] = __builtin_amdgcn_mfma_f32_16x16x32_bf16(a0.h, b0.h, acc1[ct], 0, 0, 0);
    acc1[ct] = __builtin_amdgcn_mfma_f32_16x16x32_bf16(a1.h, b1f.h, acc1[ct], 0, 0, 0);
  }
  // relu+bias -> bf16 LDS tile (D-layout scatter: row=lg*4+r, col=ct*16+l15)
#pragma unroll
  for (int ct = 0; ct < 8; ct++) {
    int col = ct * 16 + l15;
    float bias = b1[col];
#pragma unroll
    for (int r = 0; r < 4; r++) {
      float h = fmaxf(acc1[ct][r] + bias, 0.f);
      sh[wid][lg * 4 + r][col] = (unsigned short)(pack_bf2(h, 0.f) & 0xffffu);
    }
  }
  __syncthreads();
  // ---- stage 2: h1 @ W2 (A-frags from LDS: lane=row l15, k=ks*32+lg*8) ----
  FragU a[4];
#pragma unroll
  for (int ks = 0; ks < 4; ks++)
    a[ks].u = *(const uint4*)&sh[wid][l15][ks * 32 + lg * 8];
  f32x4 acc2[4];
#pragma unroll
  for (int ct = 0; ct < 4; ct++) acc2[ct] = (f32x4){0.f, 0.f, 0.f, 0.f};
#pragma unroll
  for (int ct = 0; ct < 4; ct++) {
    const uint4* wp = (const uint4*)(W2b + (size_t)(ct * 16 + l15) * 64);
#pragma unroll
    for (int ks = 0; ks < 4; ks++) {
      FragU bf;
      bf.u = wp[4 * ks + lg];
      acc2[ct] = __builtin_amdgcn_mfma_f32_16x16x32_bf16(a[ks].h, bf.h, acc2[ct], 0, 0, 0);
    }
  }
#pragma unroll
  for (int ct = 0; ct < 4; ct++) {
    int col = ct * 16 + l15;
    float bias = b2[col];
#pragma unroll
    for (int r = 0; r < 4; r++) {
      int row = rowbase + lg * 4 + r;
      if (row < NN) out[(size_t)row * 64 + col] = fmaxf(acc2[ct][r] + bias, 0.f);
    }
  }
}

// ---------------- host ----------------
extern "C" void kernel_launch(void* const* d_in, const int* in_sizes, int n_in,
                              void* d_out, int out_size, void* d_ws, size_t ws_size,
                              hipStream_t stream) {
  (void)in_sizes; (void)n_in; (void)out_size; (void)ws_size;
  const float* x        = (const float*)d_in[0];
  const int*   ei       = (const int*)d_in[1];
  const float* gcnK_W   = (const float*)d_in[2];
  const float* gcnK_b   = (const float*)d_in[3];
  const float* gcnV_W   = (const float*)d_in[4];
  const float* gcnV_b   = (const float*)d_in[5];
  const float* super_Q  = (const float*)d_in[6];
  const float* mha_in_w = (const float*)d_in[7];
  const float* mha_in_b = (const float*)d_in[8];
  const float* mha_out_w= (const float*)d_in[9];
  const float* mha_out_b= (const float*)d_in[10];
  const float* gat_W    = (const float*)d_in[11];
  const float* gat_Wc   = (const float*)d_in[12];
  const float* gat_a_src= (const float*)d_in[13];
  const float* gat_a_dst= (const float*)d_in[14];
  const float* gat_b    = (const float*)d_in[15];
  const float* t1_W     = (const float*)d_in[16];
  const float* t1_b     = (const float*)d_in[17];
  const float* t2_W     = (const float*)d_in[18];
  const float* t2_b     = (const float*)d_in[19];

  char* ws = (char*)d_ws;
  size_t cur = 0;
  auto alloc = [&](size_t bytes) -> char* {
    char* p = ws + cur;
    cur = (cur + bytes + 255) & ~(size_t)255;
    return p;
  };
  // every buffer fully written before first read, EXCEPT part2 (atomic target, memset below)
  int*      histmat = (int*)alloc((size_t)NBK * NCB * 4);
  int*      ppos    = (int*)alloc((size_t)NCB * NBK * 4);  // transposed [cb][blk]
  int*      bstart  = (int*)alloc((size_t)(NCB + 1) * 4);
  int*      offsets = (int*)alloc((size_t)(NN + 1) * 4);
  float*    dinv    = (float*)alloc((size_t)NN * 4);
  int*      csr     = (int*)alloc((size_t)EE * 4);
  unsigned* brec    = (unsigned*)alloc((size_t)EE * 4);
  unsigned* Wt      = (unsigned*)alloc((size_t)208 * 32 * 4); // bf16 fused weights, [col][k] k-paired
  float*    bb      = (float*)alloc(208 * 4);                 // fused biases (V,G,Z)
  unsigned* W1b     = (unsigned*)alloc((size_t)4096 * 4);     // bf16 t1_W [128 col][64 k] k-paired
  unsigned* W2b     = (unsigned*)alloc((size_t)4096 * 4);     // bf16 t2_W [64 col][128 k] k-paired
  float*    aeff    = (float*)alloc(64 * 4);
  float*    part2   = (float*)alloc((size_t)NS * 720 * 4);    // atomic-folded MHA partials
  float*    s_src   = (float*)alloc((size_t)NN * 4);
  float*    s_dstv  = (float*)alloc((size_t)NN * 4);
  unsigned* xbf     = (unsigned*)alloc((size_t)NN * 128);   // bf16 x*dinv
  unsigned* axb     = (unsigned*)alloc((size_t)NN * 128);   // bf16 A_norm@x
  unsigned char* hG8 = (unsigned char*)alloc((size_t)NN * 64); // fp8 GAT features (sole hg copy)
  unsigned* gb      = (unsigned*)alloc((size_t)NN * 128);   // bf16 GAT output
  float*    g       = (float*)d_out;

  hipMemsetAsync(part2, 0, (size_t)NS * 720 * 4, stream);
  k_hist<<<NBK, 256, 0, stream>>>(ei, histmat);
  k_ppos<<<NCB, 512, 0, stream>>>(histmat, bstart, offsets, ppos);
  k_fill_b<<<NBK, 256, 0, stream>>>(ei, ppos, brec);
  k_fill_c<<<NCB, 1024, 0, stream>>>(brec, bstart, csr, offsets, dinv, x, xbf);
  k_agg_x<<<NN / 4, 256, 0, stream>>>(xbf, offsets, csr, dinv, axb);
  k_fusew<<<49, 256, 0, stream>>>(gcnK_W, gcnK_b, gcnV_W, gcnV_b, mha_in_w, mha_in_b,
                                  gat_W, super_Q, t1_W, t2_W, Wt, bb, W1b, W2b);
  k_proj<<<NPROJ, 256, 0, stream>>>(axb, Wt, bb, gat_a_dst, hG8, s_dstv, part2);
  k_context<<<1, 640, 0, stream>>>(part2, mha_out_w, mha_out_b, gat_a_src, gat_Wc, aeff);
  k_ssrc<<<NN / 4, 256, 0, stream>>>(hG8, aeff, s_src);
  k_gat<<<NN / 4, 256, 0, stream>>>(offsets, csr, s_src, s_dstv, hG8, gat_b, gb);
  k_mlp<<<(NN + 63) / 64, 256, 0, stream>>>(gb, W1b, t1_b, W2b, t2_b, g);
}

// Round 16
// 376.184 us; speedup vs baseline: 1.0130x; 1.0130x over previous
//
#include <hip/hip_runtime.h>
#include <hip/hip_bf16.h>
#include <stdint.h>

#define NN 100000
#define EE 1600000
#define NBK 391        // fill blocks, 4096 edges each
#define CHUNK 4096
#define NCB 98         // coarse buckets of 1024 nodes (98*1024 >= NN)
#define NPROJ 1563     // (NN+63)/64 proj blocks
#define NS 32          // mred splits (part2 rows; k_proj atomics fold directly)

typedef __attribute__((ext_vector_type(8))) short bf16x8;
typedef __attribute__((ext_vector_type(4))) float f32x4;
typedef __attribute__((ext_vector_type(2))) float f32x2;
union FragU { uint4 u; bf16x8 h; };

__device__ inline unsigned pack_bf2(float a, float b) {
  __hip_bfloat162 t;
  t.x = __float2bfloat16(a);
  t.y = __float2bfloat16(b);
  return *reinterpret_cast<unsigned*>(&t);
}

// unpack a bf16 pair (uint) into f32x2 — 2 VALU; pairs feed v_pk_fma_f32/v_pk_add_f32
__device__ inline f32x2 unpk2(unsigned u) {
  f32x2 r;
  r.x = __uint_as_float(u << 16);
  r.y = __uint_as_float(u & 0xffff0000u);
  return r;
}

// ---------------- per-block LDS histogram over 98 coarse buckets ----------------
__launch_bounds__(256)
__global__ void k_hist(const int* __restrict__ ei, int* __restrict__ histmat) {
  __shared__ int hist[NCB];
  int t = threadIdx.x;
  if (t < NCB) hist[t] = 0;
  __syncthreads();
  int base = blockIdx.x * CHUNK;
  int nb = EE - base; if (nb > CHUNK) nb = CHUNK;
  for (int k = t; k < nb; k += 256)
    atomicAdd(&hist[ei[EE + base + k] >> 10], 1);
  __syncthreads();
  if (t < NCB) histmat[blockIdx.x * NCB + t] = hist[t];
}

// ---------------- scan stage 1: column sums (98 blocks) ----------------
__launch_bounds__(256)
__global__ void k_sumcb(const int* __restrict__ histmat, int* __restrict__ cbsum) {
  __shared__ int red[4];
  int cb = blockIdx.x, t = threadIdx.x;
  int s = 0;
  for (int blk = t; blk < NBK; blk += 256) s += histmat[blk * NCB + cb];
#pragma unroll
  for (int off = 32; off > 0; off >>= 1) s += __shfl_down(s, off);
  if ((t & 63) == 0) red[t >> 6] = s;
  __syncthreads();
  if (t == 0) cbsum[cb] = red[0] + red[1] + red[2] + red[3];
}

// ---------------- scan stage 2+3 merged: bucket bases + per-bucket cursor scan ----
__launch_bounds__(512)
__global__ void k_ppos(const int* __restrict__ histmat, const int* __restrict__ cbsum,
                       int* __restrict__ bstart, int* __restrict__ offsets,
                       int* __restrict__ ppos) {
  __shared__ int sm[512];
  __shared__ int sb[128];
  int cb = blockIdx.x, t = threadIdx.x;
  if (t < 128) sb[t] = (t < NCB) ? cbsum[t] : 0;
  __syncthreads();
  for (int off = 1; off < 128; off <<= 1) {
    int x = (t < 128 && t >= off) ? sb[t - off] : 0;
    __syncthreads();
    if (t < 128) sb[t] += x;
    __syncthreads();
  }
  int bs = (cb == 0) ? 0 : sb[cb - 1];  // exclusive prefix (inclusive scan of prev)
  if (t == 0) bstart[cb] = bs;
  if (cb == 0 && t == 0) { bstart[NCB] = EE; offsets[NN] = EE; }
  int v = (t < NBK) ? histmat[t * NCB + cb] : 0;
  sm[t] = v;
  __syncthreads();
  for (int off = 1; off < 512; off <<= 1) {
    int x = (t >= off) ? sm[t - off] : 0;
    __syncthreads();
    sm[t] += x;
    __syncthreads();
  }
  if (t < NBK) ppos[cb * NBK + t] = bs + sm[t] - v;
}

// ---------------- fill pass B: LDS radix-partition + contiguous run copy ----------------
__launch_bounds__(256)
__global__ void k_fill_b(const int* __restrict__ ei, const int* __restrict__ ppos,
                         unsigned* __restrict__ brec) {
  __shared__ int hist[NCB], binstart[NCB], bincur[NCB], pbase[NCB];
  __shared__ unsigned lbuf[CHUNK];
  __shared__ unsigned char cbArr[CHUNK];
  int t = threadIdx.x;
  int base = blockIdx.x * CHUNK;
  int nb = EE - base; if (nb > CHUNK) nb = CHUNK;
  if (t < NCB) { hist[t] = 0; pbase[t] = ppos[t * NBK + blockIdx.x]; }
  __syncthreads();
  unsigned rec[16]; int rcb[16]; int cnt = 0;
  for (int k = t; k < nb; k += 256) {
    int s = ei[base + k], d = ei[EE + base + k];
    rec[cnt] = (unsigned)s | ((unsigned)(d & 1023) << 17);  // s < 2^17, dlocal 10b
    rcb[cnt] = d >> 10;
    atomicAdd(&hist[rcb[cnt]], 1);
    cnt++;
  }
  __syncthreads();
  if (t < NCB) binstart[t] = hist[t];
  __syncthreads();
  for (int off = 1; off < NCB; off <<= 1) {
    int v = (t < NCB && t >= off) ? binstart[t - off] : 0;
    __syncthreads();
    if (t < NCB) binstart[t] += v;
    __syncthreads();
  }
  if (t < NCB) { binstart[t] -= hist[t]; bincur[t] = 0; }
  __syncthreads();
  for (int i = 0; i < cnt; i++) {
    int c = rcb[i];
    int pos = atomicAdd(&bincur[c], 1);
    int p = binstart[c] + pos;
    lbuf[p] = rec[i];
    cbArr[p] = (unsigned char)c;
  }
  __syncthreads();
  for (int i = t; i < nb; i += 256) {
    int c = cbArr[i];
    brec[pbase[c] + (i - binstart[c])] = lbuf[i];
  }
}

// ---------------- fill pass C: bucket-local histogram + scan + place ----------------
__launch_bounds__(1024)
__global__ void k_fill_c(const unsigned* __restrict__ brec, const int* __restrict__ bstart,
                         int* __restrict__ csr, int* __restrict__ offsets,
                         float* __restrict__ dinv) {
  __shared__ int cnt[1024], sm[1024];
  int cbk = blockIdx.x, t = threadIdx.x;
  int nb0 = cbk << 10;
  int nn = NN - nb0; if (nn > 1024) nn = 1024;
  cnt[t] = 0;
  __syncthreads();
  int e0 = bstart[cbk], e1 = bstart[cbk + 1];
  for (int j = e0 + t; j < e1; j += 1024)
    atomicAdd(&cnt[brec[j] >> 17], 1);
  __syncthreads();
  int cv = cnt[t];
  sm[t] = cv;
  __syncthreads();
  for (int off = 1; off < 1024; off <<= 1) {
    int v = (t >= off) ? sm[t - off] : 0;
    __syncthreads();
    sm[t] += v;
    __syncthreads();
  }
  sm[t] -= cv;  // exclusive
  if (t < nn) {
    offsets[nb0 + t] = e0 + sm[t];
    dinv[nb0 + t] = rsqrtf((float)(cv + 1));  // deg includes self loop
  }
  cnt[t] = 0;  // reuse as placement cursor
  __syncthreads();
  for (int j = e0 + t; j < e1; j += 1024) {
    unsigned r = brec[j];
    int dl = r >> 17;
    int p = atomicAdd(&cnt[dl], 1);
    csr[e0 + sm[dl] + p] = r & 0x1FFFF;  // confined to this bucket's window
  }
}

// ---------------- x~ = bf16(x * dinv[row]) ----------------
__global__ void k_prep(const float* __restrict__ x, const float* __restrict__ dinv,
                       unsigned* __restrict__ xbf2) {
  int i = blockIdx.x * 256 + threadIdx.x;  // pair index
  if (i >= NN * 32) return;
  float dv = dinv[i >> 5];
  float2 v = ((const float2*)x)[i];
  xbf2[i] = pack_bf2(v.x * dv, v.y * dv);
}

// ---------------- ax = A_norm @ x (8-lane-group gather, 2x unrolled) ----------------
__launch_bounds__(256)
__global__ void k_agg_x(const unsigned* __restrict__ xbf2, const int* __restrict__ offsets,
                        const int* __restrict__ csr, const float* __restrict__ dinv,
                        unsigned* __restrict__ axb) {
  int gid = blockIdx.x * 256 + threadIdx.x;
  int n = gid >> 6;
  if (n >= NN) return;
  int lane = gid & 63, q = lane & 7, grp = lane >> 3;
  int e0 = offsets[n], e1 = offsets[n + 1];
  float dv = dinv[n];
  f32x2 a2[4];
#pragma unroll
  for (int i = 0; i < 4; i++) a2[i] = (f32x2){0.f, 0.f};
  if (grp == 0) {  // self loop, counted once
    uint4 u = ((const uint4*)(xbf2 + (size_t)n * 32))[q];
    unsigned uu[4] = {u.x, u.y, u.z, u.w};
#pragma unroll
    for (int p = 0; p < 4; p++) a2[p] += unpk2(uu[p]);
  }
  int b2 = e0;
  for (; b2 + 8 < e1; b2 += 16) {
    int j0 = b2 + grp, j1 = j0 + 8;
    int s0 = csr[j0];
    bool ok1 = j1 < e1;
    int s1 = ok1 ? csr[j1] : s0;
    uint4 u0 = ((const uint4*)(xbf2 + (size_t)s0 * 32))[q];
    uint4 u1 = ((const uint4*)(xbf2 + (size_t)s1 * 32))[q];
    unsigned w0[4] = {u0.x, u0.y, u0.z, u0.w};
    unsigned w1[4] = {u1.x, u1.y, u1.z, u1.w};
#pragma unroll
    for (int p = 0; p < 4; p++) a2[p] += unpk2(w0[p]);
    if (ok1) {
#pragma unroll
      for (int p = 0; p < 4; p++) a2[p] += unpk2(w1[p]);
    }
  }
  for (; b2 < e1; b2 += 8) {
    int j = b2 + grp;
    if (j < e1) {
      int s = csr[j];
      uint4 u = ((const uint4*)(xbf2 + (size_t)s * 32))[q];
      unsigned uu[4] = {u.x, u.y, u.z, u.w};
#pragma unroll
      for (int p = 0; p < 4; p++) a2[p] += unpk2(uu[p]);
    }
  }
#pragma unroll
  for (int i = 0; i < 4; i++) {
    a2[i].x += __shfl_xor(a2[i].x, 8);
    a2[i].x += __shfl_xor(a2[i].x, 16);
    a2[i].x += __shfl_xor(a2[i].x, 32);
    a2[i].y += __shfl_xor(a2[i].y, 8);
    a2[i].y += __shfl_xor(a2[i].y, 16);
    a2[i].y += __shfl_xor(a2[i].y, 32);
  }
  if (lane < 8) {
    uint4 u;
    u.x = pack_bf2(a2[0].x * dv, a2[0].y * dv);
    u.y = pack_bf2(a2[1].x * dv, a2[1].y * dv);
    u.z = pack_bf2(a2[2].x * dv, a2[2].y * dv);
    u.w = pack_bf2(a2[3].x * dv, a2[3].y * dv);
    ((uint4*)(axb + (size_t)n * 32))[q] = u;
  }
}

// ---------------- fused weights + MLP weight repack ----------------
// Wt[208 cols][64 k] bf16 k-pair packed + bb[208]  (blocks 0..16)
// blocks 17..32: W1b[128 cols][64 k];  blocks 33..48: W2b[64 cols][128 k]
__launch_bounds__(256)
__global__ void k_fusew(const float* __restrict__ gcnK_W, const float* __restrict__ gcnK_b,
                        const float* __restrict__ gcnV_W, const float* __restrict__ gcnV_b,
                        const float* __restrict__ mha_in_w, const float* __restrict__ mha_in_b,
                        const float* __restrict__ gat_W, const float* __restrict__ sQ,
                        const float* __restrict__ t1W, const float* __restrict__ t2W,
                        unsigned* __restrict__ Wt, float* __restrict__ bb,
                        unsigned* __restrict__ W1b, unsigned* __restrict__ W2b) {
  __shared__ float sW1[64 * 65];   // gcnV_W (blk<16) / gcnK_W (blk16), 65-padded
  __shared__ float sW2[64 * 65];   // V-rows dense 8x64 (blk<8) / gat_W padded (blk 8-15) / K-rows padded (blk16)
  __shared__ float sW3[64 * 65];   // Q-rows padded (blk16 only)
  __shared__ float sqq[640], qhs[640], Ms[5120], kb[64];
  int blk = blockIdx.x, t = threadIdx.x;
  const float scale = 0.35355339059327373f;  // 1/sqrt(8)
  if (blk < 16) {
    for (int i = t; i < 4096; i += 256) sW1[(i >> 6) * 65 + (i & 63)] = gcnV_W[i];
    if (blk < 8) {
      // this block's 8 V columns: mha_in_w rows 128+blk*8 .. +7 (dense 8x64)
      for (int i = t; i < 512; i += 256) sW2[i] = mha_in_w[(128 + blk * 8) * 64 + i];
    } else {
      for (int i = t; i < 4096; i += 256) sW2[(i >> 6) * 65 + (i & 63)] = gat_W[i];
    }
    __syncthreads();
    int idx = blk * 256 + t;        // 0..4095
    int d = idx >> 5, kp = idx & 31;
    float v2[2];
#pragma unroll
    for (int u2 = 0; u2 < 2; u2++) {
      int k = kp * 2 + u2;
      float s = 0.f;
      if (d < 64) {
        int r = d & 7;
        for (int j = 0; j < 64; j++) s = fmaf(sW1[k * 65 + j], sW2[r * 64 + j], s);
      } else {
        int c = d - 64;
        for (int j = 0; j < 64; j++) s = fmaf(sW1[k * 65 + j], sW2[j * 65 + c], s);
      }
      v2[u2] = s;
    }
    Wt[idx] = pack_bf2(v2[0], v2[1]);
    // biases for this block's 8 output columns
    if (t < 8) {
      if (blk < 8) {
        int d0 = blk * 8 + t;
        float s = mha_in_b[128 + d0];
        for (int j = 0; j < 64; j++) s = fmaf(gcnV_b[j], sW2[t * 64 + j], s);
        bb[d0] = s;
      } else {
        int c = (blk - 8) * 8 + t;
        float s = 0.f;
        for (int j = 0; j < 64; j++) s = fmaf(gcnV_b[j], sW2[j * 65 + c], s);
        bb[64 + c] = s;
      }
    }
  } else if (blk == 16) {
    // ---- single block: Z cols + Z biases, all operands LDS-staged ----
    for (int i = t; i < 4096; i += 256) {
      int r = i >> 6, c = i & 63;
      sW1[r * 65 + c] = gcnK_W[i];
      sW2[r * 65 + c] = mha_in_w[64 * 64 + i];  // K rows 64..127
      sW3[r * 65 + c] = mha_in_w[i];            // Q rows 0..63
    }
    for (int i = t; i < 640; i += 256) sqq[i] = sQ[i];
    __syncthreads();
    // stage A: qhs[lv*64+c] = (sQ[lv]·Wq[c] + bq[c]) * scale ; kb = K-proj bias
    for (int e = t; e < 640; e += 256) {
      int lv = e >> 6, c = e & 63;
      float acc = mha_in_b[c];
      for (int i = 0; i < 64; i++) acc = fmaf(sqq[lv * 64 + i], sW3[c * 65 + i], acc);
      qhs[e] = acc * scale;
    }
    if (t < 64) {
      float s = mha_in_b[64 + t];
      for (int j = 0; j < 64; j++) s = fmaf(gcnK_b[j], sW2[t * 65 + j], s);
      kb[t] = s;
    }
    __syncthreads();
    // stage B: M[j][hl] = sum_c Wk_row(64+cp)[j] * qhs[lv][cp] ; bz
    for (int e = t; e < 5120; e += 256) {
      int j = e / 80, hl = e % 80;
      int h = hl / 10, lv = hl % 10;
      float s = 0.f;
#pragma unroll
      for (int c = 0; c < 8; c++) {
        int cp = h * 8 + c;
        s = fmaf(sW2[cp * 65 + j], qhs[lv * 64 + cp], s);
      }
      Ms[j * 80 + hl] = s;
    }
    if (t < 80) {
      int h = t / 10, lv = t % 10;
      float s = 0.f;
#pragma unroll
      for (int c = 0; c < 8; c++) {
        int cp = h * 8 + c;
        s = fmaf(kb[cp], qhs[lv * 64 + cp], s);
      }
      bb[128 + t] = s;
    }
    __syncthreads();
    // stage C: Wz[k][hl] = sum_j gcnK_W[k][j] * M[j][hl]
    for (int e = t; e < 2560; e += 256) {
      int hl = e >> 5, kp = e & 31;
      float v2[2];
#pragma unroll
      for (int u2 = 0; u2 < 2; u2++) {
        int k = kp * 2 + u2;
        float s = 0.f;
        for (int j = 0; j < 64; j++) s = fmaf(sW1[k * 65 + j], Ms[j * 80 + hl], s);
        v2[u2] = s;
      }
      Wt[(128 + hl) * 32 + kp] = pack_bf2(v2[0], v2[1]);
    }
  } else if (blk < 33) {
    // ---- W1b: t1_W [64 k][128 c] -> [col][k] bf16 k-pair packed ----
    int idx = (blk - 17) * 256 + t;   // 0..4095
    int col = idx >> 5, kp = idx & 31;
    W1b[idx] = pack_bf2(t1W[(2 * kp) * 128 + col], t1W[(2 * kp + 1) * 128 + col]);
  } else {
    // ---- W2b: t2_W [128 k][64 c] -> [col][k] bf16 k-pair packed ----
    int idx = (blk - 33) * 256 + t;   // 0..4095
    int col = idx >> 6, kp = idx & 63;
    W2b[idx] = pack_bf2(t2W[(2 * kp) * 64 + col], t2W[(2 * kp + 1) * 64 + col]);
  }
}

// ---------------- k_proj (MFMA): X[64x64] @ Wt^T[64x208] -> V,G,Z tiles ----------------
__launch_bounds__(256)
__global__ void k_proj(const unsigned* __restrict__ axb, const unsigned* __restrict__ Wt,
                       const float* __restrict__ bb, const float* __restrict__ a_dst,
                       unsigned char* __restrict__ hG8,
                       float* __restrict__ s_dstv, float* __restrict__ part2) {
  __shared__ float red[4][720];                 // 11520 B  per-wave s/o partials
  int t = threadIdx.x;
  int wid = t >> 6, l = t & 63;
  int l15 = l & 15, lg = l >> 4;
  int base = blockIdx.x * 64;
  int rowbase = base + wid * 16;

  // ---- A fragments (2 K-steps), rows >= NN zeroed ----
  FragU a0, a1;
  {
    int r = rowbase + l15;
    if (r < NN) {
      const uint4* p = (const uint4*)(axb + (size_t)r * 32);
      a0.u = p[lg];
      a1.u = p[4 + lg];
    } else {
      a0.u = make_uint4(0u, 0u, 0u, 0u);
      a1.u = a0.u;
    }
  }
  // ---- GEMM: 13 col-tiles x 2 K-steps ----
  f32x4 acc[13];
#pragma unroll
  for (int ct = 0; ct < 13; ct++) acc[ct] = (f32x4){0.f, 0.f, 0.f, 0.f};
#pragma unroll
  for (int ct = 0; ct < 13; ct++) {
    const uint4* wp = (const uint4*)(Wt + (size_t)(ct * 16 + l15) * 32);
    FragU b0, b1;
    b0.u = wp[lg];
    b1.u = wp[4 + lg];
    acc[ct] = __builtin_amdgcn_mfma_f32_16x16x32_bf16(a0.h, b0.h, acc[ct], 0, 0, 0);
    acc[ct] = __builtin_amdgcn_mfma_f32_16x16x32_bf16(a1.h, b1.h, acc[ct], 0, 0, 0);
  }

  // ---- G epilogue: hg = acc+bias -> fp8 store + sd = hg . a_dst ----
  float sdp[4] = {0.f, 0.f, 0.f, 0.f};
#pragma unroll
  for (int gt = 0; gt < 4; gt++) {
    int col = gt * 16 + l15;
    float bias = bb[64 + col];
    float ad = a_dst[col];
#pragma unroll
    for (int r = 0; r < 4; r++) {
      float hg = acc[4 + gt][r] + bias;
      sdp[r] = fmaf(hg, ad, sdp[r]);
      int row = rowbase + lg * 4 + r;
      if (row < NN) {
        unsigned wq = __builtin_amdgcn_cvt_pk_fp8_f32(hg, hg, 0u, false);
        hG8[(size_t)row * 64 + col] = (unsigned char)(wq & 0xffu);
      }
    }
  }
#pragma unroll
  for (int r = 0; r < 4; r++) {
    float v = sdp[r];
    v += __shfl_xor(v, 1); v += __shfl_xor(v, 2);
    v += __shfl_xor(v, 4); v += __shfl_xor(v, 8);
    int row = rowbase + lg * 4 + r;
    if (l15 == 0 && row < NN) s_dstv[row] = v;
  }

  // ---- Z phase: w = exp(z) kept in REGISTERS; s partials -> red (exact f32) ----
  float wz[5][4];
#pragma unroll
  for (int zt = 0; zt < 5; zt++) {
    int zcol = zt * 16 + l15;       // 0..79 = h*10+lv
    float bias = bb[128 + zcol];
    float sp = 0.f;
#pragma unroll
    for (int r = 0; r < 4; r++) {
      int row = rowbase + lg * 4 + r;
      float z = acc[8 + zt][r] + bias;
      float w = (row < NN) ? __expf(z) : 0.f;
      wz[zt][r] = w;
      sp += w;
    }
    sp += __shfl_xor(sp, 16);
    sp += __shfl_xor(sp, 32);
    if (l < 16) {
      int h = zcol / 10, lv = zcol % 10;
      red[wid][h * 90 + lv] = sp;
    }
  }

  // ---- O phase on matrix pipe: o[hl][c] = sum_row w[row][hl]*vv[row][c] ----
  int sA = (l15 + 32 * lg) & 63;        // source lane for rows 8lg..8lg+3
  int sB2 = (sA + 16) & 63;             // source lane for rows 8lg+4..8lg+7
  bool loK = (lg < 2);
  FragU af[5];
#pragma unroll
  for (int zt = 0; zt < 5; zt++) {
    unsigned wlo = pack_bf2(wz[zt][0], wz[zt][1]);
    unsigned whi = pack_bf2(wz[zt][2], wz[zt][3]);
    unsigned f0 = __shfl(wlo, sA), f1 = __shfl(whi, sA);
    unsigned f2 = __shfl(wlo, sB2), f3 = __shfl(whi, sB2);
    af[zt].u.x = loK ? f0 : 0u;
    af[zt].u.y = loK ? f1 : 0u;
    af[zt].u.z = loK ? f2 : 0u;
    af[zt].u.w = loK ? f3 : 0u;
  }
#pragma unroll
  for (int vt = 0; vt < 4; vt++) {
    float bias = bb[vt * 16 + l15];
    unsigned vlo = pack_bf2(acc[vt][0] + bias, acc[vt][1] + bias);
    unsigned vhi = pack_bf2(acc[vt][2] + bias, acc[vt][3] + bias);
    FragU bf;
    {
      unsigned f0 = __shfl(vlo, sA), f1 = __shfl(vhi, sA);
      unsigned f2 = __shfl(vlo, sB2), f3 = __shfl(vhi, sB2);
      bf.u.x = loK ? f0 : 0u;
      bf.u.y = loK ? f1 : 0u;
      bf.u.z = loK ? f2 : 0u;
      bf.u.w = loK ? f3 : 0u;
    }
    f32x4 oacc[5];
#pragma unroll
    for (int zt = 0; zt < 5; zt++) {
      oacc[zt] = (f32x4){0.f, 0.f, 0.f, 0.f};
      oacc[zt] = __builtin_amdgcn_mfma_f32_16x16x32_bf16(af[zt].h, bf.h, oacc[zt], 0, 0, 0);
    }
    // D-layout: o[hl = zt*16+lg*4+reg][c = vt*16+l15]; keep only head-matched c
#pragma unroll
    for (int zt = 0; zt < 5; zt++) {
#pragma unroll
      for (int r = 0; r < 4; r++) {
        int hl = zt * 16 + lg * 4 + r;
        int h = hl / 10, lv = hl - h * 10;
        if (vt * 2 + (l15 >> 3) == h)
          red[wid][h * 90 + 10 + lv * 8 + (l15 & 7)] = oacc[zt][r];
      }
    }
  }

  // ---- fold 4 waves -> part2 split (atomic; coalesced per block) ----
  __syncthreads();
  float* p2 = part2 + (size_t)(blockIdx.x & (NS - 1)) * 720;
  for (int j = t; j < 720; j += 256) {
    float v = red[0][j] + red[1][j] + red[2][j] + red[3][j];
    atomicAdd(&p2[j], v);
  }
}

// ---------------- context (merged mred2): fold 32 splits -> softmax -> a_eff ----
__global__ void k_context(const float* __restrict__ part2, const float* __restrict__ out_w,
                          const float* __restrict__ out_b, const float* __restrict__ a_src,
                          const float* __restrict__ gat_Wc, float* __restrict__ aeff) {
  __shared__ float po[640], cl[640], ctx[64], ac[720];
  int t = threadIdx.x;  // blockDim = 640
  for (int j = t; j < 720; j += 640) {
    float v = 0.f;
#pragma unroll
    for (int s = 0; s < NS; s++) v += part2[(size_t)s * 720 + j];
    int cg = j / 90, r = j % 90;
    ac[(r < 10) ? (cg * 10 + r) : (80 + cg * 80 + (r - 10))] = v;
  }
  __syncthreads();
  {
    int h = t / 80, r = t % 80, l = r >> 3, j = r & 7;
    po[l * 64 + h * 8 + j] = ac[80 + t] / ac[h * 10 + l];
  }
  __syncthreads();
  {
    int l = t >> 6, d = t & 63;
    float v = out_b[d];
    for (int c = 0; c < 64; c++) v = fmaf(po[l * 64 + c], out_w[d * 64 + c], v);
    cl[t] = v;
  }
  __syncthreads();
  if (t < 64) {
    float m = 0.f;
#pragma unroll
    for (int l = 0; l < 10; l++) m += cl[l * 64 + t];
    ctx[t] = m * 0.1f;
  }
  __syncthreads();
  if (t < 64) {
    float v = a_src[t];
    for (int i = 0; i < 64; i++) v = fmaf(ctx[i], gat_Wc[i * 64 + t], v);
    aeff[t] = v;
  }
}

// ---------------- s_src[n] = dot(hG8[n], a_eff)  (fp8 rows) ----------------
__launch_bounds__(256)
__global__ void k_ssrc(const unsigned char* __restrict__ hG8, const float* __restrict__ aeff,
                       float* __restrict__ s_src) {
  int gid = blockIdx.x * 256 + threadIdx.x;
  int n = gid >> 6, lane = gid & 63;
  if (n >= NN) return;
  unsigned b = hG8[(size_t)n * 64 + lane];
  float v = __builtin_amdgcn_cvt_f32_fp8(b, 0) * aeff[lane];
#pragma unroll
  for (int off = 32; off > 0; off >>= 1) v += __shfl_xor(v, off);
  if (lane == 0) s_src[n] = v;
}

// ---------------- GAT: 8-lane-group gather over fp8 rows -> bf16 output ----------------
__launch_bounds__(256)
__global__ void k_gat(const int* __restrict__ offsets, const int* __restrict__ csr,
                      const float* __restrict__ s_src, const float* __restrict__ s_dstv,
                      const unsigned char* __restrict__ hG8, const float* __restrict__ gat_b,
                      unsigned* __restrict__ gb) {
  int gid = blockIdx.x * 256 + threadIdx.x;
  int n = gid >> 6;
  if (n >= NN) return;
  int lane = gid & 63, q = lane & 7, grp = lane >> 3;
  int e0 = offsets[n], e1 = offsets[n + 1];
  float sd = s_dstv[n];
  float den = 0.f;
  f32x2 a2[4];
#pragma unroll
  for (int i = 0; i < 4; i++) a2[i] = (f32x2){0.f, 0.f};
  int b2 = e0;
  for (; b2 + 8 < e1; b2 += 16) {
    int j0 = b2 + grp, j1 = j0 + 8;
    int s0 = csr[j0];
    bool ok1 = j1 < e1;
    int s1 = ok1 ? csr[j1] : s0;
    float z0 = s_src[s0] + sd;
    float z1 = s_src[s1] + sd;
    uint2 u0 = ((const uint2*)(hG8 + (size_t)s0 * 64))[q];
    uint2 u1 = ((const uint2*)(hG8 + (size_t)s1 * 64))[q];
    z0 = z0 > 0.f ? z0 : 0.2f * z0;
    float ex0 = __expf(z0);  // logits O(1): softmax shift-invariant, skip segment-max
    den += ex0;
    f32x2 e0v = (f32x2){ex0, ex0};
    {
      f32x2 p0 = __builtin_amdgcn_cvt_pk_f32_fp8(u0.x, false);
      f32x2 p1 = __builtin_amdgcn_cvt_pk_f32_fp8(u0.x, true);
      f32x2 p2 = __builtin_amdgcn_cvt_pk_f32_fp8(u0.y, false);
      f32x2 p3 = __builtin_amdgcn_cvt_pk_f32_fp8(u0.y, true);
      a2[0] = e0v * p0 + a2[0];
      a2[1] = e0v * p1 + a2[1];
      a2[2] = e0v * p2 + a2[2];
      a2[3] = e0v * p3 + a2[3];
    }
    if (ok1) {
      z1 = z1 > 0.f ? z1 : 0.2f * z1;
      float ex1 = __expf(z1);
      den += ex1;
      f32x2 e1v = (f32x2){ex1, ex1};
      f32x2 p0 = __builtin_amdgcn_cvt_pk_f32_fp8(u1.x, false);
      f32x2 p1 = __builtin_amdgcn_cvt_pk_f32_fp8(u1.x, true);
      f32x2 p2 = __builtin_amdgcn_cvt_pk_f32_fp8(u1.y, false);
      f32x2 p3 = __builtin_amdgcn_cvt_pk_f32_fp8(u1.y, true);
      a2[0] = e1v * p0 + a2[0];
      a2[1] = e1v * p1 + a2[1];
      a2[2] = e1v * p2 + a2[2];
      a2[3] = e1v * p3 + a2[3];
    }
  }
  for (; b2 < e1; b2 += 8) {
    int j = b2 + grp;
    if (j < e1) {
      int s = csr[j];
      float z = s_src[s] + sd;
      z = z > 0.f ? z : 0.2f * z;
      float ex = __expf(z);
      den += ex;
      uint2 u = ((const uint2*)(hG8 + (size_t)s * 64))[q];
      f32x2 ev = (f32x2){ex, ex};
      f32x2 p0 = __builtin_amdgcn_cvt_pk_f32_fp8(u.x, false);
      f32x2 p1 = __builtin_amdgcn_cvt_pk_f32_fp8(u.x, true);
      f32x2 p2 = __builtin_amdgcn_cvt_pk_f32_fp8(u.y, false);
      f32x2 p3 = __builtin_amdgcn_cvt_pk_f32_fp8(u.y, true);
      a2[0] = ev * p0 + a2[0];
      a2[1] = ev * p1 + a2[1];
      a2[2] = ev * p2 + a2[2];
      a2[3] = ev * p3 + a2[3];
    }
  }
  den += __shfl_xor(den, 8);
  den += __shfl_xor(den, 16);
  den += __shfl_xor(den, 32);
#pragma unroll
  for (int i = 0; i < 4; i++) {
    a2[i].x += __shfl_xor(a2[i].x, 8);
    a2[i].x += __shfl_xor(a2[i].x, 16);
    a2[i].x += __shfl_xor(a2[i].x, 32);
    a2[i].y += __shfl_xor(a2[i].y, 8);
    a2[i].y += __shfl_xor(a2[i].y, 16);
    a2[i].y += __shfl_xor(a2[i].y, 32);
  }
  float inv = 1.f / (den + 1e-16f);
  if (lane < 8) {
    uint4 u;
    u.x = pack_bf2(a2[0].x * inv + gat_b[q * 8 + 0], a2[0].y * inv + gat_b[q * 8 + 1]);
    u.y = pack_bf2(a2[1].x * inv + gat_b[q * 8 + 2], a2[1].y * inv + gat_b[q * 8 + 3]);
    u.z = pack_bf2(a2[2].x * inv + gat_b[q * 8 + 4], a2[2].y * inv + gat_b[q * 8 + 5]);
    u.w = pack_bf2(a2[3].x * inv + gat_b[q * 8 + 6], a2[3].y * inv + gat_b[q * 8 + 7]);
    ((uint4*)(gb + (size_t)n * 32))[q] = u;
  }
}

// ---------------- MLP stage 1 (MFMA): h1 = relu(g @ W1 + b1) -> bf16 ----------------
__launch_bounds__(256)
__global__ void k_mlp1(const unsigned* __restrict__ gb, const unsigned* __restrict__ W1b,
                       const float* __restrict__ b1, unsigned* __restrict__ h1b) {
  int t = threadIdx.x;
  int wid = t >> 6, l = t & 63;
  int l15 = l & 15, lg = l >> 4;
  int rowbase = blockIdx.x * 64 + wid * 16;
  FragU a0, a1;
  {
    int r = rowbase + l15;
    if (r < NN) {
      const uint4* p = (const uint4*)(gb + (size_t)r * 32);
      a0.u = p[lg];
      a1.u = p[4 + lg];
    } else {
      a0.u = make_uint4(0u, 0u, 0u, 0u);
      a1.u = a0.u;
    }
  }
  f32x4 acc[8];
#pragma unroll
  for (int ct = 0; ct < 8; ct++) acc[ct] = (f32x4){0.f, 0.f, 0.f, 0.f};
#pragma unroll
  for (int ct = 0; ct < 8; ct++) {
    const uint4* wp = (const uint4*)(W1b + (size_t)(ct * 16 + l15) * 32);
    FragU b0, b1f;
    b0.u = wp[lg];
    b1f.u = wp[4 + lg];
    acc[ct] = __builtin_amdgcn_mfma_f32_16x16x32_bf16(a0.h, b0.h, acc[ct], 0, 0, 0);
    acc[ct] = __builtin_amdgcn_mfma_f32_16x16x32_bf16(a1.h, b1f.h, acc[ct], 0, 0, 0);
  }
  __hip_bfloat16* hp = (__hip_bfloat16*)h1b;
#pragma unroll
  for (int ct = 0; ct < 8; ct++) {
    int col = ct * 16 + l15;
    float bias = b1[col];
#pragma unroll
    for (int r = 0; r < 4; r++) {
      int row = rowbase + lg * 4 + r;
      if (row < NN) hp[(size_t)row * 128 + col] = __float2bfloat16(fmaxf(acc[ct][r] + bias, 0.f));
    }
  }
}

// ---------------- MLP stage 2 (MFMA): out = relu(h1 @ W2 + b2) -> f32 ----------------
__launch_bounds__(256)
__global__ void k_mlp2(const unsigned* __restrict__ h1b, const unsigned* __restrict__ W2b,
                       const float* __restrict__ b2, float* __restrict__ out) {
  int t = threadIdx.x;
  int wid = t >> 6, l = t & 63;
  int l15 = l & 15, lg = l >> 4;
  int rowbase = blockIdx.x * 64 + wid * 16;
  FragU a[4];
  {
    int r = rowbase + l15;
    if (r < NN) {
      const uint4* p = (const uint4*)(h1b + (size_t)r * 64);
#pragma unroll
      for (int ks = 0; ks < 4; ks++) a[ks].u = p[4 * ks + lg];
    } else {
#pragma unroll
      for (int ks = 0; ks < 4; ks++) a[ks].u = make_uint4(0u, 0u, 0u, 0u);
    }
  }
  f32x4 acc[4];
#pragma unroll
  for (int ct = 0; ct < 4; ct++) acc[ct] = (f32x4){0.f, 0.f, 0.f, 0.f};
#pragma unroll
  for (int ct = 0; ct < 4; ct++) {
    const uint4* wp = (const uint4*)(W2b + (size_t)(ct * 16 + l15) * 64);
#pragma unroll
    for (int ks = 0; ks < 4; ks++) {
      FragU bf;
      bf.u = wp[4 * ks + lg];
      acc[ct] = __builtin_amdgcn_mfma_f32_16x16x32_bf16(a[ks].h, bf.h, acc[ct], 0, 0, 0);
    }
  }
#pragma unroll
  for (int ct = 0; ct < 4; ct++) {
    int col = ct * 16 + l15;
    float bias = b2[col];
#pragma unroll
    for (int r = 0; r < 4; r++) {
      int row = rowbase + lg * 4 + r;
      if (row < NN) out[(size_t)row * 64 + col] = fmaxf(acc[ct][r] + bias, 0.f);
    }
  }
}

// ---------------- host ----------------
extern "C" void kernel_launch(void* const* d_in, const int* in_sizes, int n_in,
                              void* d_out, int out_size, void* d_ws, size_t ws_size,
                              hipStream_t stream) {
  (void)in_sizes; (void)n_in; (void)out_size; (void)ws_size;
  const float* x        = (const float*)d_in[0];
  const int*   ei       = (const int*)d_in[1];
  const float* gcnK_W   = (const float*)d_in[2];
  const float* gcnK_b   = (const float*)d_in[3];
  const float* gcnV_W   = (const float*)d_in[4];
  const float* gcnV_b   = (const float*)d_in[5];
  const float* super_Q  = (const float*)d_in[6];
  const float* mha_in_w = (const float*)d_in[7];
  const float* mha_in_b = (const float*)d_in[8];
  const float* mha_out_w= (const float*)d_in[9];
  const float* mha_out_b= (const float*)d_in[10];
  const float* gat_W    = (const float*)d_in[11];
  const float* gat_Wc   = (const float*)d_in[12];
  const float* gat_a_src= (const float*)d_in[13];
  const float* gat_a_dst= (const float*)d_in[14];
  const float* gat_b    = (const float*)d_in[15];
  const float* t1_W     = (const float*)d_in[16];
  const float* t1_b     = (const float*)d_in[17];
  const float* t2_W     = (const float*)d_in[18];
  const float* t2_b     = (const float*)d_in[19];

  char* ws = (char*)d_ws;
  size_t cur = 0;
  auto alloc = [&](size_t bytes) -> char* {
    char* p = ws + cur;
    cur = (cur + bytes + 255) & ~(size_t)255;
    return p;
  };
  // every buffer fully written before first read, EXCEPT part2 (atomic target, memset below)
  int*      histmat = (int*)alloc((size_t)NBK * NCB * 4);
  int*      cbsum   = (int*)alloc((size_t)NCB * 4);
  int*      ppos    = (int*)alloc((size_t)NCB * NBK * 4);  // transposed [cb][blk]
  int*      bstart  = (int*)alloc((size_t)(NCB + 1) * 4);
  int*      offsets = (int*)alloc((size_t)(NN + 1) * 4);
  float*    dinv    = (float*)alloc((size_t)NN * 4);
  int*      csr     = (int*)alloc((size_t)EE * 4);
  unsigned* brec    = (unsigned*)alloc((size_t)EE * 4);
  unsigned* Wt      = (unsigned*)alloc((size_t)208 * 32 * 4); // bf16 fused weights, [col][k] k-paired
  float*    bb      = (float*)alloc(208 * 4);                 // fused biases (V,G,Z)
  unsigned* W1b     = (unsigned*)alloc((size_t)4096 * 4);     // bf16 t1_W [128 col][64 k] k-paired
  unsigned* W2b     = (unsigned*)alloc((size_t)4096 * 4);     // bf16 t2_W [64 col][128 k] k-paired
  float*    aeff    = (float*)alloc(64 * 4);
  float*    part2   = (float*)alloc((size_t)NS * 720 * 4);    // atomic-folded MHA partials
  float*    s_src   = (float*)alloc((size_t)NN * 4);
  float*    s_dstv  = (float*)alloc((size_t)NN * 4);
  unsigned* xbf     = (unsigned*)alloc((size_t)NN * 128);   // bf16 x*dinv
  unsigned* axb     = (unsigned*)alloc((size_t)NN * 128);   // bf16 A_norm@x
  unsigned char* hG8 = (unsigned char*)alloc((size_t)NN * 64); // fp8 GAT features (sole hg copy)
  unsigned* gb      = (unsigned*)alloc((size_t)NN * 128);   // bf16 GAT output
  unsigned* h1b     = (unsigned*)alloc((size_t)NN * 64 * 4); // bf16 MLP hidden (128/row)
  float*    g       = (float*)d_out;

  hipMemsetAsync(part2, 0, (size_t)NS * 720 * 4, stream);
  k_hist<<<NBK, 256, 0, stream>>>(ei, histmat);
  k_sumcb<<<NCB, 256, 0, stream>>>(histmat, cbsum);
  k_ppos<<<NCB, 512, 0, stream>>>(histmat, cbsum, bstart, offsets, ppos);
  k_fill_b<<<NBK, 256, 0, stream>>>(ei, ppos, brec);
  k_fill_c<<<NCB, 1024, 0, stream>>>(brec, bstart, csr, offsets, dinv);
  k_prep<<<(NN * 32 + 255) / 256, 256, 0, stream>>>(x, dinv, xbf);
  k_agg_x<<<NN / 4, 256, 0, stream>>>(xbf, offsets, csr, dinv, axb);
  k_fusew<<<49, 256, 0, stream>>>(gcnK_W, gcnK_b, gcnV_W, gcnV_b, mha_in_w, mha_in_b,
                                  gat_W, super_Q, t1_W, t2_W, Wt, bb, W1b, W2b);
  k_proj<<<NPROJ, 256, 0, stream>>>(axb, Wt, bb, gat_a_dst, hG8, s_dstv, part2);
  k_context<<<1, 640, 0, stream>>>(part2, mha_out_w, mha_out_b, gat_a_src, gat_Wc, aeff);
  k_ssrc<<<NN / 4, 256, 0, stream>>>(hG8, aeff, s_src);
  k_gat<<<NN / 4, 256, 0, stream>>>(offsets, csr, s_src, s_dstv, hG8, gat_b, gb);
  k_mlp1<<<(NN + 63) / 64, 256, 0, stream>>>(gb, W1b, t1_b, h1b);
  k_mlp2<<<(NN + 63) / 64, 256, 0, stream>>>(h1b, W2b, t2_b, g);
}